// Round 1
// baseline (76.601 us; speedup 1.0000x reference)
//
#include <hip/hip_runtime.h>

// Problem constants (match reference)
#define MAX_ATOMS   80
#define MAX_DEGREE  4
#define MAX_RINGS   10
#define RING_SIZE   8
#define RING_FLAT   (MAX_RINGS * RING_SIZE)   // 80
#define EDGE_FLAT   (MAX_ATOMS * MAX_DEGREE)  // 320
#define MOLS_PER_BLOCK 4                      // 1 wave (64 lanes) per molecule

__device__ __forceinline__ float bond_val(int nb, unsigned ma, const unsigned* m) {
    // nb in [-1, 80). Clamp for a safe LDS read; validity via nb >= 0.
    int c = nb < 0 ? 0 : (nb > MAX_ATOMS - 1 ? MAX_ATOMS - 1 : nb);
    unsigned hit = (nb >= 0) ? (ma & m[c]) : 0u;
    return hit ? 1.0f : 0.0f;
}

__global__ __launch_bounds__(256) void Find_Ring_Bonds_kernel(
    const float* __restrict__ edges,   // [B, 80, 4] float (int values, -1 = null)
    const int*   __restrict__ rings,   // [B, 10, 8] int  (-1 = pad)
    float*       __restrict__ out,     // [B, 80, 4, 1] float
    int B)
{
    __shared__ unsigned mask[MOLS_PER_BLOCK][MAX_ATOMS];

    const int wave = threadIdx.x >> 6;
    const int lane = threadIdx.x & 63;
    const int mol  = blockIdx.x * MOLS_PER_BLOCK + wave;
    const bool live = (mol < B);

    unsigned* m = mask[wave];

    // Phase 0: zero the per-molecule atom->ringmask table (80 entries)
    if (live) {
        m[lane] = 0u;
        if (lane < MAX_ATOMS - 64) m[64 + lane] = 0u;
    }
    __syncthreads();

    // Phase 1: scatter ring membership. Flat ring index i -> ring r = i>>3.
    if (live) {
        const int* ring = rings + (size_t)mol * RING_FLAT;
        int v0 = ring[lane];
        if (v0 >= 0) atomicOr(&m[v0], 1u << (lane >> 3));
        if (lane < RING_FLAT - 64) {
            int i1 = 64 + lane;
            int v1 = ring[i1];
            if (v1 >= 0) atomicOr(&m[v1], 1u << (i1 >> 3));
        }
    }
    __syncthreads();

    // Phase 2: per-atom float4 edge pass (coalesced 16B/lane loads + stores)
    if (live) {
        const float4* e4 = (const float4*)(edges + (size_t)mol * EDGE_FLAT);
        float4*       o4 = (float4*)(out + (size_t)mol * EDGE_FLAT);

        {
            int a = lane;                       // atoms 0..63
            float4 ev = e4[a];
            unsigned ma = m[a];
            float4 r;
            r.x = bond_val((int)ev.x, ma, m);
            r.y = bond_val((int)ev.y, ma, m);
            r.z = bond_val((int)ev.z, ma, m);
            r.w = bond_val((int)ev.w, ma, m);
            o4[a] = r;
        }
        if (lane < MAX_ATOMS - 64) {            // atoms 64..79
            int a = 64 + lane;
            float4 ev = e4[a];
            unsigned ma = m[a];
            float4 r;
            r.x = bond_val((int)ev.x, ma, m);
            r.y = bond_val((int)ev.y, ma, m);
            r.z = bond_val((int)ev.z, ma, m);
            r.w = bond_val((int)ev.w, ma, m);
            o4[a] = r;
        }
    }
}

extern "C" void kernel_launch(void* const* d_in, const int* in_sizes, int n_in,
                              void* d_out, int out_size, void* d_ws, size_t ws_size,
                              hipStream_t stream) {
    const float* edges = (const float*)d_in[0];   // [B,80,4] float32
    const int*   rings = (const int*)d_in[1];     // [B,10,8] int32
    float*       out   = (float*)d_out;           // [B,80,4,1] float32

    const int B = in_sizes[0] / EDGE_FLAT;        // 16384
    const int grid = (B + MOLS_PER_BLOCK - 1) / MOLS_PER_BLOCK;

    Find_Ring_Bonds_kernel<<<grid, 256, 0, stream>>>(edges, rings, out, B);
}